// Round 7
// baseline (349.414 us; speedup 1.0000x reference)
//
#include <hip/hip_runtime.h>
#include <math.h>

#define BB 4
#define SS 8192
#define HH 16
#define DD 64
#define ROT 32
#define NG (BB * SS * HH)  // 524288 token-head rows
#define WT 16              // rows per WAVE-tile (= one token: 16 heads)
#define TPB 512            // 8 waves per block, each wave autonomous
#define XSTR 65            // stripe row stride (pad +1)

typedef float f32x4 __attribute__((ext_vector_type(4)));  // native vec for NT store

// ---------------------------------------------------------------------------
// Merged setup: G_comb = I @ G_0 @ ... @ G_31 built in LDS (threads 0..63,
// column-op per row, no syncs needed among them), then M = G @ matrix.
// i==j edge: .at chain leaves G[i,i]=sin -> column i scaled by sin.
// ---------------------------------------------------------------------------
__global__ void setup_GM(const float* __restrict__ thetas,
                         const float* __restrict__ tscale,
                         const int* __restrict__ pairs,
                         const float* __restrict__ matrix,
                         float* __restrict__ M) {
  __shared__ float Gs[DD][DD];
  const int t = threadIdx.x;
  if (t < DD) {
    for (int c = 0; c < DD; ++c) Gs[t][c] = (t == c) ? 1.0f : 0.0f;
    const float ts = tscale[0];
    for (int r = 0; r < ROT; ++r) {
      const int i = pairs[2 * r], j = pairs[2 * r + 1];
      const float th = thetas[r] * ts;
      const float cc = cosf(th), sn = sinf(th);
      if (i == j) {
        Gs[t][i] *= sn;
      } else {
        const float a = Gs[t][i], b = Gs[t][j];
        Gs[t][i] = a * cc + b * sn;
        Gs[t][j] = b * cc - a * sn;
      }
    }
  }
  __syncthreads();
  const int e = blockIdx.x * 256 + t;
  const int row = e >> 6, col = e & 63;  // row wave-uniform -> LDS broadcast
  float a0 = 0.f, a1 = 0.f, a2 = 0.f, a3 = 0.f;
  for (int k = 0; k < DD; k += 4) {
    a0 = fmaf(Gs[row][k], matrix[k * DD + col], a0);
    a1 = fmaf(Gs[row][k + 1], matrix[(k + 1) * DD + col], a1);
    a2 = fmaf(Gs[row][k + 2], matrix[(k + 2) * DD + col], a2);
    a3 = fmaf(Gs[row][k + 3], matrix[(k + 3) * DD + col], a3);
  }
  M[e] = (a0 + a1) + (a2 + a3);
}

// cos/sin table PRESCALED by 32 (the sqrt(dims) factor fused here).
// tab[s*64 + d] = 32*cos(s*invf[d]); tab[s*64 + 32 + d] = 32*sin(...)
__global__ void setup_table(const float* __restrict__ invf,
                            float* __restrict__ tab) {
  const int idx = blockIdx.x * 256 + threadIdx.x;
  if (idx >= SS * 32) return;
  const int s = idx >> 5, d = idx & 31;
  const float ang = (float)s * invf[d];
  tab[s * 64 + d] = 32.0f * cosf(ang);
  tab[s * 64 + 32 + d] = 32.0f * sinf(ang);
}

// ---------------------------------------------------------------------------
// Main kernel, ZERO steady-state barriers (wave-autonomous).
// Theory: R0-R6 (occupancy 29-77%, blocks/CU 2-8, all pipeline flavors) all
// land 102-127 us -> the invariant limiter is the block-wide barrier convoy.
// Here each WAVE owns one 16-row tile (= all 16 heads of one token, so the
// RoPE position is wave-uniform). Lane (r2=l&7, h8=l>>3) computes rows
// {2r2, 2r2+1} x cols [8h8, 8h8+8). M lives in LDS (staged once per block,
// the only __syncthreads); per-lane M reads are 8-way broadcast ds_read_b128
// on 2-way-aliased banks (free). Outputs go DIRECTLY to global: the store
// lane map tiles full 128B lines (8 lanes x 16B contiguous per row), so all
// 4 store instructions are fully coalesced 1KB NT stores - no restage.
// Accumulation order per element (k ascending) identical to R0-R6.
// ---------------------------------------------------------------------------
__global__ __launch_bounds__(TPB, 6) void apply_rot(
    const float* __restrict__ x, const float* __restrict__ M,
    const float* __restrict__ tab, const float* __restrict__ invf,
    float* __restrict__ out) {
  __shared__ float Ml[DD * DD];      // 16384 B, shared by all 8 waves
  __shared__ float xs[8][WT * XSTR]; // 8 x 4160 B wave-private stripes
  const int tid = threadIdx.x;
  const int w = tid >> 6;   // wave id 0..7
  const int l = tid & 63;   // lane

  // Prologue: stage M (2 float4/thread) + this wave's 16 rows of x.
  {
    const float4* __restrict__ M4 = (const float4*)M;
    *(float4*)&Ml[tid * 4] = M4[tid];
    *(float4*)&Ml[(512 + tid) * 4] = M4[512 + tid];
  }
  const size_t T0 = ((size_t)blockIdx.x * 8 + w) * WT;  // first row of tile
  float* __restrict__ xw = xs[w];
  {
    const float4* __restrict__ xg = (const float4*)x + T0 * 16;
#pragma unroll
    for (int i = 0; i < 4; ++i) {
      const int f = i * 64 + l;  // float4 idx in 4KB tile
      *(float4*)&xw[(f >> 4) * XSTR + (f & 15) * 4] = xg[f];
    }
  }
  __syncthreads();  // ONLY barrier: Ml visibility (xw is same-wave)

  // Compute: lane (r2, h8) -> rows {2r2, 2r2+1}, cols [8h8, 8h8+8).
  const int r2 = l & 7;
  const int h8 = l >> 3;
  const float* __restrict__ xr0 = &xw[(2 * r2) * XSTR];
  const float* __restrict__ xr1 = &xw[(2 * r2 + 1) * XSTR];

  float acc0[8], acc1[8];
#pragma unroll
  for (int c = 0; c < 8; ++c) acc0[c] = acc1[c] = 0.0f;

#pragma unroll 4
  for (int k4 = 0; k4 < 16; ++k4) {
    const float4 xa = *(const float4*)&xr0[k4 * 4];
    const float4 xb = *(const float4*)&xr1[k4 * 4];
#pragma unroll
    for (int kk = 0; kk < 4; ++kk) {
      const float4 m0 = *(const float4*)&Ml[(k4 * 4 + kk) * DD + 8 * h8];
      const float4 m1 = *(const float4*)&Ml[(k4 * 4 + kk) * DD + 8 * h8 + 4];
      const float xak = ((const float*)&xa)[kk];
      const float xbk = ((const float*)&xb)[kk];
      acc0[0] = fmaf(xak, m0.x, acc0[0]);
      acc0[1] = fmaf(xak, m0.y, acc0[1]);
      acc0[2] = fmaf(xak, m0.z, acc0[2]);
      acc0[3] = fmaf(xak, m0.w, acc0[3]);
      acc0[4] = fmaf(xak, m1.x, acc0[4]);
      acc0[5] = fmaf(xak, m1.y, acc0[5]);
      acc0[6] = fmaf(xak, m1.z, acc0[6]);
      acc0[7] = fmaf(xak, m1.w, acc0[7]);
      acc1[0] = fmaf(xbk, m0.x, acc1[0]);
      acc1[1] = fmaf(xbk, m0.y, acc1[1]);
      acc1[2] = fmaf(xbk, m0.z, acc1[2]);
      acc1[3] = fmaf(xbk, m0.w, acc1[3]);
      acc1[4] = fmaf(xbk, m1.x, acc1[4]);
      acc1[5] = fmaf(xbk, m1.y, acc1[5]);
      acc1[6] = fmaf(xbk, m1.z, acc1[6]);
      acc1[7] = fmaf(xbk, m1.w, acc1[7]);
    }
  }

  // RoPE epilogue. Tile = one token -> spos wave-uniform; d = 4h8 + j.
  const int spos = (int)((T0 >> 4) & (SS - 1));
  float cz[4], sz[4];
  if (tab) {
    *(float4*)cz = *(const float4*)(tab + spos * 64 + 4 * h8);
    *(float4*)sz = *(const float4*)(tab + spos * 64 + 32 + 4 * h8);
  } else {
#pragma unroll
    for (int j = 0; j < 4; ++j) {
      const float ang = (float)spos * invf[4 * h8 + j];
      cz[j] = 32.0f * cosf(ang);
      sz[j] = 32.0f * sinf(ang);
    }
  }

  float4 lo0, hi0, lo1, hi1;
#pragma unroll
  for (int j = 0; j < 4; ++j) {
    const float e0 = acc0[2 * j], o0 = acc0[2 * j + 1];
    const float e1 = acc1[2 * j], o1 = acc1[2 * j + 1];
    ((float*)&lo0)[j] = e0 * cz[j] - o0 * sz[j];
    ((float*)&hi0)[j] = e0 * sz[j] + o0 * cz[j];
    ((float*)&lo1)[j] = e1 * cz[j] - o1 * sz[j];
    ((float*)&hi1)[j] = e1 * sz[j] + o1 * cz[j];
  }

  // Direct coalesced NT stores: per instr, lanes of equal r2 (8 of them,
  // h8=0..7) tile one row's 128B line contiguously -> 8 full lines/instr.
  float* __restrict__ o0 = out + (T0 + 2 * r2) * DD;
  float* __restrict__ o1 = o0 + DD;
  __builtin_nontemporal_store(*(const f32x4*)&lo0, (f32x4*)(o0 + 4 * h8));
  __builtin_nontemporal_store(*(const f32x4*)&hi0, (f32x4*)(o0 + 32 + 4 * h8));
  __builtin_nontemporal_store(*(const f32x4*)&lo1, (f32x4*)(o1 + 4 * h8));
  __builtin_nontemporal_store(*(const f32x4*)&hi1, (f32x4*)(o1 + 32 + 4 * h8));
}

// ---------------------------------------------------------------------------
extern "C" void kernel_launch(void* const* d_in, const int* in_sizes, int n_in,
                              void* d_out, int out_size, void* d_ws,
                              size_t ws_size, hipStream_t stream) {
  const float* x = (const float*)d_in[0];       // (4, 8192, 1024) f32
  const float* matrix = (const float*)d_in[1];  // (64, 64) f32
  const float* thetas = (const float*)d_in[2];  // (32,) f32
  const float* tscale = (const float*)d_in[3];  // (1,) f32
  const float* invf = (const float*)d_in[4];    // (32,) f32
  const int* pairs = (const int*)d_in[5];       // (32, 2) i32
  float* out = (float*)d_out;

  float* M = (float*)d_ws;   // 4096 f
  float* tab = M + DD * DD;  // SS*64 f = 2 MB
  const size_t need = (size_t)(DD * DD + SS * 64) * sizeof(float);
  const bool have_tab = ws_size >= need;

  setup_GM<<<16, 256, 0, stream>>>(thetas, tscale, pairs, matrix, M);
  if (have_tab) setup_table<<<(SS * 32) / 256, 256, 0, stream>>>(invf, tab);
  apply_rot<<<NG / (WT * 8), TPB, 0, stream>>>(x, M, have_tab ? tab : nullptr,
                                               invf, out);
}

// Round 8
// 330.307 us; speedup vs baseline: 1.0578x; 1.0578x over previous
//
#include <hip/hip_runtime.h>
#include <math.h>

#define BB 4
#define SS 8192
#define HH 16
#define DD 64
#define ROT 32
#define NG (BB * SS * HH)  // 524288 token-head rows
#define WR 64              // rows per wave (= block): lane l owns row l
#define LSTR 65            // LDS row stride in floats (pad +1 -> 2-way banks)
#define TPB 64             // ONE wave per block: zero barriers anywhere

typedef float f32x4 __attribute__((ext_vector_type(4)));  // native vec for NT store

// ---------------------------------------------------------------------------
// Merged setup: G_comb = I @ G_0 @ ... @ G_31 built in LDS (threads 0..63,
// column-op per row, no syncs needed among them), then M = G @ matrix.
// i==j edge: .at chain leaves G[i,i]=sin -> column i scaled by sin.
// ---------------------------------------------------------------------------
__global__ void setup_GM(const float* __restrict__ thetas,
                         const float* __restrict__ tscale,
                         const int* __restrict__ pairs,
                         const float* __restrict__ matrix,
                         float* __restrict__ M) {
  __shared__ float Gs[DD][DD];
  const int t = threadIdx.x;
  if (t < DD) {
    for (int c = 0; c < DD; ++c) Gs[t][c] = (t == c) ? 1.0f : 0.0f;
    const float ts = tscale[0];
    for (int r = 0; r < ROT; ++r) {
      const int i = pairs[2 * r], j = pairs[2 * r + 1];
      const float th = thetas[r] * ts;
      const float cc = cosf(th), sn = sinf(th);
      if (i == j) {
        Gs[t][i] *= sn;
      } else {
        const float a = Gs[t][i], b = Gs[t][j];
        Gs[t][i] = a * cc + b * sn;
        Gs[t][j] = b * cc - a * sn;
      }
    }
  }
  __syncthreads();
  const int e = blockIdx.x * 256 + t;
  const int row = e >> 6, col = e & 63;  // row wave-uniform -> LDS broadcast
  float a0 = 0.f, a1 = 0.f, a2 = 0.f, a3 = 0.f;
  for (int k = 0; k < DD; k += 4) {
    a0 = fmaf(Gs[row][k], matrix[k * DD + col], a0);
    a1 = fmaf(Gs[row][k + 1], matrix[(k + 1) * DD + col], a1);
    a2 = fmaf(Gs[row][k + 2], matrix[(k + 2) * DD + col], a2);
    a3 = fmaf(Gs[row][k + 3], matrix[(k + 3) * DD + col], a3);
  }
  M[e] = (a0 + a1) + (a2 + a3);
}

// cos/sin table PRESCALED by 32 (the sqrt(dims) factor fused here).
// tab[s*64 + d] = 32*cos(s*invf[d]); tab[s*64 + 32 + d] = 32*sin(...)
__global__ void setup_table(const float* __restrict__ invf,
                            float* __restrict__ tab) {
  const int idx = blockIdx.x * 256 + threadIdx.x;
  if (idx >= SS * 32) return;
  const int s = idx >> 5, d = idx & 31;
  const float ang = (float)s * invf[d];
  tab[s * 64 + d] = 32.0f * cosf(ang);
  tab[s * 64 + 32 + d] = 32.0f * sinf(ang);
}

// ---------------------------------------------------------------------------
// Main kernel: ZERO barriers + scalar-pipe M (the combination R0-R7 never
// had together). One wave per block owns 64 rows; lane l owns row l.
// R7 autopsy: per-lane M through LDS serialized the CU's single LDS pipe
// (~102 us). Here M stays on s_load (free scalar broadcasts, proven R0-R6),
// which REQUIRES the col-stripe h to be wave-uniform -> h is a fully
// unrolled uniform loop 0..3, lane covers all 64 cols of its row. x is
// staged in wave-private LDS (16.6 KB -> 9 free-running waves/CU, no
// convoy); per-lane LDS traffic is only 112 ds-ops/tile (~17 us/CU total,
// not binding). Per-stripe outputs buffer in statically-indexed registers
// (h unrolled), restage through the then-dead x LDS, leave as full-line NT
// stores. Accumulation order (k ascending per output) identical to R0-R6
// -> bitwise-same result.
// ---------------------------------------------------------------------------
__global__ __launch_bounds__(TPB, 4) void apply_rot(
    const float* __restrict__ x, const float* __restrict__ M,
    const float* __restrict__ tab, const float* __restrict__ invf,
    float* __restrict__ out) {
  __shared__ float lds[WR * LSTR];  // 16640 B, wave-private
  const int l = threadIdx.x;        // lane = row
  const size_t T0 = (size_t)blockIdx.x * WR;

  // Stage 64 rows, fully coalesced (16 x 1KB loads), padded LDS.
  const float4* __restrict__ xg = (const float4*)x + T0 * 16;
#pragma unroll
  for (int j = 0; j < 16; ++j) {
    const int f = j * 64 + l;
    *(float4*)&lds[(f >> 4) * LSTR + (f & 15) * 4] = xg[f];
  }
  // No barrier: same-wave DS ordering covers ds_write -> ds_read.

  const int spos = (int)(((T0 + l) >> 4) & (SS - 1));  // per-lane token pos
  const float* __restrict__ xr = &lds[l * LSTR];

  float4 obl[4][2], obh[4][2];  // per-stripe outputs; h unrolled -> static idx

#pragma unroll
  for (int h = 0; h < 4; ++h) {
    const float* __restrict__ Mh = M + h * 16;
    float acc[16];
#pragma unroll
    for (int c = 0; c < 16; ++c) acc[c] = 0.0f;

#pragma unroll 4
    for (int k4 = 0; k4 < 16; ++k4) {
      const float4 xv = *(const float4*)&xr[k4 * 4];
      const float* __restrict__ m0 = Mh + k4 * 4 * DD;  // uniform -> s_load
#pragma unroll
      for (int c = 0; c < 16; ++c) acc[c] = fmaf(xv.x, m0[c], acc[c]);
#pragma unroll
      for (int c = 0; c < 16; ++c) acc[c] = fmaf(xv.y, m0[DD + c], acc[c]);
#pragma unroll
      for (int c = 0; c < 16; ++c) acc[c] = fmaf(xv.z, m0[2 * DD + c], acc[c]);
#pragma unroll
      for (int c = 0; c < 16; ++c) acc[c] = fmaf(xv.w, m0[3 * DD + c], acc[c]);
    }

    // RoPE factors for this stripe: d = 8h..8h+8, per-lane spos (L2-hot tab).
    float cz[8], sz[8];
    if (tab) {
      const float* __restrict__ tb = tab + spos * 64 + 8 * h;
      *(float4*)&cz[0] = *(const float4*)(tb);
      *(float4*)&cz[4] = *(const float4*)(tb + 4);
      *(float4*)&sz[0] = *(const float4*)(tb + 32);
      *(float4*)&sz[4] = *(const float4*)(tb + 36);
    } else {
#pragma unroll
      for (int d = 0; d < 8; ++d) {
        const float ang = (float)spos * invf[8 * h + d];
        cz[d] = 32.0f * cosf(ang);
        sz[d] = 32.0f * sinf(ang);
      }
    }

    // Pairs (2d',2d'+1) within stripe -> lo (out col d) / hi (out col 32+d).
#pragma unroll
    for (int q = 0; q < 2; ++q) {
#pragma unroll
      for (int d = 0; d < 4; ++d) {
        const int dd = 4 * q + d;
        const float e = acc[2 * dd], o = acc[2 * dd + 1];
        ((float*)&obl[h][q])[d] = e * cz[dd] - o * sz[dd];
        ((float*)&obh[h][q])[d] = e * sz[dd] + o * cz[dd];
      }
    }
  }

  // x fully consumed -> reuse LDS: assemble output row l, then coalesced
  // full-line NT stores. Same-wave DS ordering; still no barrier.
  float* __restrict__ orow = &lds[l * LSTR];
#pragma unroll
  for (int h = 0; h < 4; ++h) {
    *(float4*)&orow[8 * h] = obl[h][0];
    *(float4*)&orow[8 * h + 4] = obl[h][1];
    *(float4*)&orow[32 + 8 * h] = obh[h][0];
    *(float4*)&orow[32 + 8 * h + 4] = obh[h][1];
  }

  float4* __restrict__ og = (float4*)out + T0 * 16;
#pragma unroll
  for (int j = 0; j < 16; ++j) {
    const int f = j * 64 + l;
    const float4 v = *(const float4*)&lds[(f >> 4) * LSTR + (f & 15) * 4];
    __builtin_nontemporal_store(*(const f32x4*)&v, (f32x4*)&og[f]);
  }
}

// ---------------------------------------------------------------------------
extern "C" void kernel_launch(void* const* d_in, const int* in_sizes, int n_in,
                              void* d_out, int out_size, void* d_ws,
                              size_t ws_size, hipStream_t stream) {
  const float* x = (const float*)d_in[0];       // (4, 8192, 1024) f32
  const float* matrix = (const float*)d_in[1];  // (64, 64) f32
  const float* thetas = (const float*)d_in[2];  // (32,) f32
  const float* tscale = (const float*)d_in[3];  // (1,) f32
  const float* invf = (const float*)d_in[4];    // (32,) f32
  const int* pairs = (const int*)d_in[5];       // (32, 2) i32
  float* out = (float*)d_out;

  float* M = (float*)d_ws;   // 4096 f
  float* tab = M + DD * DD;  // SS*64 f = 2 MB
  const size_t need = (size_t)(DD * DD + SS * 64) * sizeof(float);
  const bool have_tab = ws_size >= need;

  setup_GM<<<16, 256, 0, stream>>>(thetas, tscale, pairs, matrix, M);
  if (have_tab) setup_table<<<(SS * 32) / 256, 256, 0, stream>>>(invf, tab);
  apply_rot<<<NG / WR, TPB, 0, stream>>>(x, M, have_tab ? tab : nullptr, invf,
                                         out);
}

// Round 9
// 286.736 us; speedup vs baseline: 1.2186x; 1.1520x over previous
//
#include <hip/hip_runtime.h>
#include <math.h>

#define BB 4
#define SS 8192
#define HH 16
#define DD 64
#define ROT 32
#define NG (BB * SS * HH)  // 524288 token-head rows
#define RPB 64             // rows per tile
#define LSTR 65            // LDS row stride in floats (pad +1 -> rotated banks)
#define TPB 256            // 4 waves per block
#define TILES 4            // tiles per block (contiguous)
#define NBLK (NG / (RPB * TILES))  // 2048 blocks

typedef float f32x4 __attribute__((ext_vector_type(4)));  // native vec for NT store

// lgkm-only barrier: LDS visibility without draining global loads/stores
// (correctness-proven in R5; prefetch loads + NT stores stay in flight).
#define BAR() asm volatile("s_waitcnt lgkmcnt(0)\n\ts_barrier" ::: "memory")

// ---------------------------------------------------------------------------
// Merged setup: G_comb = I @ G_0 @ ... @ G_31 built in LDS (threads 0..63,
// column-op per row, no syncs needed among them), then M = G @ matrix.
// i==j edge: .at chain leaves G[i,i]=sin -> column i scaled by sin.
// ---------------------------------------------------------------------------
__global__ void setup_GM(const float* __restrict__ thetas,
                         const float* __restrict__ tscale,
                         const int* __restrict__ pairs,
                         const float* __restrict__ matrix,
                         float* __restrict__ M) {
  __shared__ float Gs[DD][DD];
  const int t = threadIdx.x;
  if (t < DD) {
    for (int c = 0; c < DD; ++c) Gs[t][c] = (t == c) ? 1.0f : 0.0f;
    const float ts = tscale[0];
    for (int r = 0; r < ROT; ++r) {
      const int i = pairs[2 * r], j = pairs[2 * r + 1];
      const float th = thetas[r] * ts;
      const float cc = cosf(th), sn = sinf(th);
      if (i == j) {
        Gs[t][i] *= sn;
      } else {
        const float a = Gs[t][i], b = Gs[t][j];
        Gs[t][i] = a * cc + b * sn;
        Gs[t][j] = b * cc - a * sn;
      }
    }
  }
  __syncthreads();
  const int e = blockIdx.x * 256 + t;
  const int row = e >> 6, col = e & 63;  // row wave-uniform -> LDS broadcast
  float a0 = 0.f, a1 = 0.f, a2 = 0.f, a3 = 0.f;
  for (int k = 0; k < DD; k += 4) {
    a0 = fmaf(Gs[row][k], matrix[k * DD + col], a0);
    a1 = fmaf(Gs[row][k + 1], matrix[(k + 1) * DD + col], a1);
    a2 = fmaf(Gs[row][k + 2], matrix[(k + 2) * DD + col], a2);
    a3 = fmaf(Gs[row][k + 3], matrix[(k + 3) * DD + col], a3);
  }
  M[e] = (a0 + a1) + (a2 + a3);
}

// cos/sin table PRESCALED by 32 (the sqrt(dims) factor fused here).
// tab[s*64 + d] = 32*cos(s*invf[d]); tab[s*64 + 32 + d] = 32*sin(...)
__global__ void setup_table(const float* __restrict__ invf,
                            float* __restrict__ tab) {
  const int idx = blockIdx.x * 256 + threadIdx.x;
  if (idx >= SS * 32) return;
  const int s = idx >> 5, d = idx & 31;
  const float ang = (float)s * invf[d];
  tab[s * 64 + d] = 32.0f * cosf(ang);
  tab[s * 64 + 32 + d] = 32.0f * sinf(ang);
}

// ---------------------------------------------------------------------------
// Main kernel: R6's proven body + cross-tile prefetch with the ISSUE POINT
// PINNED by sched_barrier(0). Diagnosis (R0-R8): every resource <=35us but
// dur ~= the SUM (~100us) -> phases fully serialized; R3/R5's source-level
// prefetch was SUNK by the compiler to its use (VGPR=60 evidence), so loads
// always fired inside the staging phase, fully exposed. Here:
//   stage st -> lds (waits loads issued ~2000cyc ago: ~0 stall)
//   BAR1 (lgkm-only: in-flight vmem survives)
//   issue tab(t), then x(t+1) -> st; sched_barrier(0)  <- cannot sink
//   compute matvec (ds_read + s_load M + FMA) ; epilogue (counted vmcnt
//     waits tab only; x stays in flight -> in-order retirement)
//   BAR2 ; outputs -> lds ; BAR3 ; NT store (never drained: younger than
//     any load anyone waits on)
// Per-thread store/stage slots identical (fa map) -> no barrier between
// store-read and next stage-write. 3 lgkm BARs/tile.
// ---------------------------------------------------------------------------
__global__ __launch_bounds__(TPB, 4) void apply_rot(
    const float* __restrict__ x, const float* __restrict__ M,
    const float* __restrict__ tab, const float* __restrict__ invf,
    float* __restrict__ out) {
  __shared__ float lds[RPB * LSTR];  // 16640 B
  const int tid = threadIdx.x;
  const int r = tid & (RPB - 1);
  const int h = __builtin_amdgcn_readfirstlane(tid >> 6);  // 0..3, wave-uniform
  const float* __restrict__ Mh = M + h * 16;
  const size_t tile0 = (size_t)blockIdx.x * TILES;

  // Per-thread LDS float-offsets for the stage/store f-map.
  int fa[4];
#pragma unroll
  for (int i = 0; i < 4; ++i) {
    const int f = i * TPB + tid;
    fa[i] = (f >> 4) * LSTR + (f & 15) * 4;
  }

  // Prologue: issue x(tile0) loads.
  float4 st0, st1, st2, st3;
  {
    const float4* __restrict__ xg = (const float4*)x + tile0 * (RPB * 16);
    st0 = xg[0 * TPB + tid];
    st1 = xg[1 * TPB + tid];
    st2 = xg[2 * TPB + tid];
    st3 = xg[3 * TPB + tid];
  }

#pragma unroll 1
  for (int t = 0; t < TILES; ++t) {
    const size_t tile = tile0 + t;
    const int g = (int)(tile * RPB) + r;
    const int spos = (g >> 4) & (SS - 1);

    // Stage current x tile (compiler waits the old loads here; they were
    // issued ~a full compute-phase ago, so the wait is ~free).
    *(float4*)&lds[fa[0]] = st0;
    *(float4*)&lds[fa[1]] = st1;
    *(float4*)&lds[fa[2]] = st2;
    *(float4*)&lds[fa[3]] = st3;
    BAR();  // BAR1: staged tile visible block-wide

    // EARLY ISSUE, pinned: tab(t) first (older -> counted-vmcnt waits for it
    // without draining x), then x(t+1). sched_barrier(0) forbids sinking.
    float cz[8], sz[8];
    if (tab) {
      const float* __restrict__ tb = tab + spos * 64 + 8 * h;
      *(float4*)&cz[0] = *(const float4*)(tb);
      *(float4*)&cz[4] = *(const float4*)(tb + 4);
      *(float4*)&sz[0] = *(const float4*)(tb + 32);
      *(float4*)&sz[4] = *(const float4*)(tb + 36);
    }
    if (t + 1 < TILES) {
      const float4* __restrict__ xn =
          (const float4*)x + (tile + 1) * (RPB * 16);
      st0 = xn[0 * TPB + tid];
      st1 = xn[1 * TPB + tid];
      st2 = xn[2 * TPB + tid];
      st3 = xn[3 * TPB + tid];
    }
    __builtin_amdgcn_sched_barrier(0);

    // Compute: thread (r,h) computes cols [16h, 16h+16) of row r.
    const float* __restrict__ xr = &lds[r * LSTR];
    float acc[16];
#pragma unroll
    for (int c = 0; c < 16; ++c) acc[c] = 0.0f;

#pragma unroll 4
    for (int k4 = 0; k4 < 16; ++k4) {
      const float4 xv = *(const float4*)&xr[k4 * 4];
      const float* __restrict__ m0 = Mh + k4 * 4 * DD;  // uniform -> s_load
#pragma unroll
      for (int c = 0; c < 16; ++c) acc[c] = fmaf(xv.x, m0[c], acc[c]);
#pragma unroll
      for (int c = 0; c < 16; ++c) acc[c] = fmaf(xv.y, m0[DD + c], acc[c]);
#pragma unroll
      for (int c = 0; c < 16; ++c) acc[c] = fmaf(xv.z, m0[2 * DD + c], acc[c]);
#pragma unroll
      for (int c = 0; c < 16; ++c) acc[c] = fmaf(xv.w, m0[3 * DD + c], acc[c]);
    }

    if (!tab) {
#pragma unroll
      for (int d = 0; d < 8; ++d) {
        const float ang = (float)spos * invf[8 * h + d];
        cz[d] = 32.0f * cosf(ang);
        sz[d] = 32.0f * sinf(ang);
      }
    }

    // RoPE epilogue: pairs (2d,2d+1) -> out cols d (lo), 32+d (hi), d=8h+d'.
    float4 lov[2], hiv[2];
#pragma unroll
    for (int q = 0; q < 2; ++q) {
#pragma unroll
      for (int d = 0; d < 4; ++d) {
        const int dd = 4 * q + d;
        const float e = acc[2 * dd], o = acc[2 * dd + 1];
        ((float*)&lov[q])[d] = e * cz[dd] - o * sz[dd];
        ((float*)&hiv[q])[d] = e * sz[dd] + o * cz[dd];
      }
    }

    BAR();  // BAR2: all lds x-reads complete before overwrite

    // Outputs -> lds (same padded layout).
    float* __restrict__ orow = &lds[r * LSTR];
    *(float4*)&orow[8 * h + 0] = lov[0];
    *(float4*)&orow[8 * h + 4] = lov[1];
    *(float4*)&orow[32 + 8 * h + 0] = hiv[0];
    *(float4*)&orow[32 + 8 * h + 4] = hiv[1];

    BAR();  // BAR3: output tile assembled

    // Coalesced NT stores (fire-and-forget; younger than every load that
    // anything waits on -> never drained inside the loop).
    float4* __restrict__ og = (float4*)out + tile * (RPB * 16);
#pragma unroll
    for (int i = 0; i < 4; ++i) {
      const float4 v = *(const float4*)&lds[fa[i]];
      __builtin_nontemporal_store(*(const f32x4*)&v,
                                  (f32x4*)&og[i * TPB + tid]);
    }
    // Next stage-write hits the same per-thread fa slots just read -> no BAR.
  }
}

// ---------------------------------------------------------------------------
extern "C" void kernel_launch(void* const* d_in, const int* in_sizes, int n_in,
                              void* d_out, int out_size, void* d_ws,
                              size_t ws_size, hipStream_t stream) {
  const float* x = (const float*)d_in[0];       // (4, 8192, 1024) f32
  const float* matrix = (const float*)d_in[1];  // (64, 64) f32
  const float* thetas = (const float*)d_in[2];  // (32,) f32
  const float* tscale = (const float*)d_in[3];  // (1,) f32
  const float* invf = (const float*)d_in[4];    // (32,) f32
  const int* pairs = (const int*)d_in[5];       // (32, 2) i32
  float* out = (float*)d_out;

  float* M = (float*)d_ws;   // 4096 f
  float* tab = M + DD * DD;  // SS*64 f = 2 MB
  const size_t need = (size_t)(DD * DD + SS * 64) * sizeof(float);
  const bool have_tab = ws_size >= need;

  setup_GM<<<16, 256, 0, stream>>>(thetas, tscale, pairs, matrix, M);
  if (have_tab) setup_table<<<(SS * 32) / 256, 256, 0, stream>>>(invf, tab);
  apply_rot<<<NBLK, TPB, 0, stream>>>(x, M, have_tab ? tab : nullptr, invf,
                                      out);
}

// Round 10
// 263.224 us; speedup vs baseline: 1.3274x; 1.0893x over previous
//
#include <hip/hip_runtime.h>
#include <math.h>

#define BB 4
#define SS 8192
#define HH 16
#define DD 64
#define ROT 32
#define NG (BB * SS * HH)  // 524288 token-head rows
#define RPT 64             // rows per tile (4 tokens; wave = 1 token)
#define TILES 4            // tiles per block
#define NBLK (NG / (RPT * TILES))  // 2048 blocks
#define TPB 256            // 4 waves
#define OSTR 65            // output restage stride (pad +1)
#define LSTR 65            // fallback kernel LDS stride

typedef float f32x4 __attribute__((ext_vector_type(4)));
typedef short bf16x8 __attribute__((ext_vector_type(8)));  // 8 bf16 = 4 VGPR

// ---------------------------------------------------------------------------
// Setup: G_comb (threads 0..63, column-op per row), then M = G @ matrix.
// ALSO emits M split into bf16 hi/lo in MFMA B-fragment layout:
//   B[k][col], lane = ((k>>3)&3)*16 + (col&15), frag = (col>>4)*2 + (k>>5),
//   elem j = k&7.  hi = truncate-to-bf16(val), lo = truncate(val - hi).
// i==j edge: .at chain leaves G[i,i]=sin -> column i scaled by sin.
// ---------------------------------------------------------------------------
__global__ void setup_GM(const float* __restrict__ thetas,
                         const float* __restrict__ tscale,
                         const int* __restrict__ pairs,
                         const float* __restrict__ matrix,
                         float* __restrict__ M,
                         unsigned short* __restrict__ Mhi,
                         unsigned short* __restrict__ Mlo) {
  __shared__ float Gs[DD][DD];
  const int t = threadIdx.x;
  if (t < DD) {
    for (int c = 0; c < DD; ++c) Gs[t][c] = (t == c) ? 1.0f : 0.0f;
    const float ts = tscale[0];
    for (int r = 0; r < ROT; ++r) {
      const int i = pairs[2 * r], j = pairs[2 * r + 1];
      const float th = thetas[r] * ts;
      const float cc = cosf(th), sn = sinf(th);
      if (i == j) {
        Gs[t][i] *= sn;
      } else {
        const float a = Gs[t][i], b = Gs[t][j];
        Gs[t][i] = a * cc + b * sn;
        Gs[t][j] = b * cc - a * sn;
      }
    }
  }
  __syncthreads();
  const int e = blockIdx.x * 256 + t;
  const int k = e >> 6, col = e & 63;  // k wave-uniform -> LDS broadcast
  float a0 = 0.f, a1 = 0.f, a2 = 0.f, a3 = 0.f;
  for (int kk = 0; kk < DD; kk += 4) {
    a0 = fmaf(Gs[k][kk], matrix[kk * DD + col], a0);
    a1 = fmaf(Gs[k][kk + 1], matrix[(kk + 1) * DD + col], a1);
    a2 = fmaf(Gs[k][kk + 2], matrix[(kk + 2) * DD + col], a2);
    a3 = fmaf(Gs[k][kk + 3], matrix[(kk + 3) * DD + col], a3);
  }
  const float val = (a0 + a1) + (a2 + a3);
  M[e] = val;

  const int K2 = k >> 5, T = col >> 4;
  const int lane = ((k >> 3) & 3) * 16 + (col & 15);
  const int idx = ((T * 2 + K2) * 64 + lane) * 8 + (k & 7);
  const unsigned int b = __float_as_uint(val);
  const unsigned int hb = b & 0xFFFF0000u;
  const float rem = val - __uint_as_float(hb);
  Mhi[idx] = (unsigned short)(b >> 16);
  Mlo[idx] = (unsigned short)(__float_as_uint(rem) >> 16);
}

// cos/sin table PRESCALED by 32 (the sqrt(dims) factor fused here).
__global__ void setup_table(const float* __restrict__ invf,
                            float* __restrict__ tab) {
  const int idx = blockIdx.x * 256 + threadIdx.x;
  if (idx >= SS * 32) return;
  const int s = idx >> 5, d = idx & 31;
  const float ang = (float)s * invf[d];
  tab[s * 64 + d] = 32.0f * cosf(ang);
  tab[s * 64 + 32 + d] = 32.0f * sinf(ang);
}

// --- split-bf16 helpers (truncation: hi = top 16 bits; rem exact in f32) ---
__device__ __forceinline__ unsigned int pack_hi(float u, float v, float& ru,
                                                float& rv) {
  const unsigned int bu = __float_as_uint(u);
  const unsigned int bv = __float_as_uint(v);
  const unsigned int hv = bv & 0xFFFF0000u;
  ru = u - __uint_as_float(bu & 0xFFFF0000u);
  rv = v - __uint_as_float(hv);
  return (bu >> 16) | hv;
}
__device__ __forceinline__ unsigned int pack_lo(float ru, float rv) {
  return (__float_as_uint(ru) >> 16) | (__float_as_uint(rv) & 0xFFFF0000u);
}
// 8 consecutive k-values (a.x..a.w, b.x..b.w) -> bf16x8 hi + lo frags.
__device__ __forceinline__ void cvt8(const f32x4 a, const f32x4 b, bf16x8& hi,
                                     bf16x8& lo) {
  unsigned int* hp = (unsigned int*)&hi;
  unsigned int* lp = (unsigned int*)&lo;
  float r0, r1;
  hp[0] = pack_hi(a[0], a[1], r0, r1);
  lp[0] = pack_lo(r0, r1);
  hp[1] = pack_hi(a[2], a[3], r0, r1);
  lp[1] = pack_lo(r0, r1);
  hp[2] = pack_hi(b[0], b[1], r0, r1);
  lp[2] = pack_lo(r0, r1);
  hp[3] = pack_hi(b[2], b[3], r0, r1);
  lp[3] = pack_lo(r0, r1);
}

// ---------------------------------------------------------------------------
// Main kernel (MFMA split-bf16). Per wave = one token (16 rows) per tile:
//  - M resident in 64 VGPRs as 8 hi + 8 lo B-frags (loaded once per block):
//    NO s_load / LDS in the K-loop (R0-R9's invariant stall source).
//  - x loaded DIRECT from global in A-frag order (4 dwordx4/lane/tile),
//    split hi/lo, 24 mfma_f32_16x16x32_bf16 (hh + h*lo + lo*h) -> ~fp32.
//  - RoPE: C layout col=l&15 -> pair partner is lane^1 (shfl_xor),
//    cz/sz uniform per wave-token; results restaged via wave-private LDS
//    (same-wave ds ordering -> ZERO barriers) -> coalesced NT stores.
// ---------------------------------------------------------------------------
__global__ __launch_bounds__(TPB, 2) void apply_rot(
    const float* __restrict__ x, const unsigned short* __restrict__ Mhi,
    const unsigned short* __restrict__ Mlo, const float* __restrict__ tab,
    float* __restrict__ out) {
  __shared__ float po[4 * 16 * OSTR];  // per-wave output restage, 16.6 KB
  const int tid = threadIdx.x;
  const int w = tid >> 6;   // wave 0..3 = token within tile
  const int l = tid & 63;   // lane
  const int l15 = l & 15, lk = l >> 4;
  const int odd = l & 1;
  const int dloc = l15 >> 1;

  // M fragments: hi/lo, frag f = (colT*2 + K2). 16 coalesced dwordx4 loads.
  bf16x8 bh[8], bl[8];
#pragma unroll
  for (int f = 0; f < 8; ++f) {
    bh[f] = *(const bf16x8*)(Mhi + (f * 64 + l) * 8);
    bl[f] = *(const bf16x8*)(Mlo + (f * 64 + l) * 8);
  }

  const size_t R0 = (size_t)blockIdx.x * (RPT * TILES);
  // This lane's x source: row = R0 + t*64 + w*16 + l15, float col lk*8 (+K2*32)
  const float* __restrict__ xp = x + (R0 + w * 16 + l15) * DD + lk * 8;
  float* __restrict__ pw = po + w * 16 * OSTR;  // wave-private LDS region

  // Prologue: issue tile-0 x loads.
  f32x4 x0 = *(const f32x4*)(xp);
  f32x4 x1 = *(const f32x4*)(xp + 4);
  f32x4 x2 = *(const f32x4*)(xp + 32);
  f32x4 x3 = *(const f32x4*)(xp + 36);

#pragma unroll 1
  for (int t = 0; t < TILES; ++t) {
    // Convert current x to A-frags (hi/lo per K2 half).
    bf16x8 ah0, al0, ah1, al1;
    cvt8(x0, x1, ah0, al0);
    cvt8(x2, x3, ah1, al1);

    // Issue next tile's loads now -> in flight under MFMA + epilogue.
    if (t + 1 < TILES) {
      xp += RPT * DD;
      x0 = *(const f32x4*)(xp);
      x1 = *(const f32x4*)(xp + 4);
      x2 = *(const f32x4*)(xp + 32);
      x3 = *(const f32x4*)(xp + 36);
    }

    // 24 MFMA on the (previously idle) matrix pipe.
    f32x4 acc[4];
#pragma unroll
    for (int T = 0; T < 4; ++T) {
      f32x4 a = {0.f, 0.f, 0.f, 0.f};
      a = __builtin_amdgcn_mfma_f32_16x16x32_bf16(ah0, bh[T * 2 + 0], a, 0, 0, 0);
      a = __builtin_amdgcn_mfma_f32_16x16x32_bf16(ah1, bh[T * 2 + 1], a, 0, 0, 0);
      a = __builtin_amdgcn_mfma_f32_16x16x32_bf16(ah0, bl[T * 2 + 0], a, 0, 0, 0);
      a = __builtin_amdgcn_mfma_f32_16x16x32_bf16(ah1, bl[T * 2 + 1], a, 0, 0, 0);
      a = __builtin_amdgcn_mfma_f32_16x16x32_bf16(al0, bh[T * 2 + 0], a, 0, 0, 0);
      a = __builtin_amdgcn_mfma_f32_16x16x32_bf16(al1, bh[T * 2 + 1], a, 0, 0, 0);
      acc[T] = a;
    }

    // RoPE epilogue. token = R0/16 + t*4 + w (wave-uniform spos).
    const int spos = (int)((R0 >> 4) + t * 4 + w) & (SS - 1);
    const float* __restrict__ tb = tab + spos * 64;
#pragma unroll
    for (int T = 0; T < 4; ++T) {
      const float cz = tb[8 * T + dloc];         // prescaled x32
      const float sz = tb[32 + 8 * T + dloc];
      const int ocol = (odd ? 32 : 0) + 8 * T + dloc;
#pragma unroll
      for (int q = 0; q < 4; ++q) {
        const float v = acc[T][q];
        const float p = __shfl_xor(v, 1);  // pair partner (col ^ 1)
        const float ps = p * sz;
        // even lane (col=2d): e*cz - o*sz ; odd lane (col=2d+1): e*sz + o*cz
        const float res = fmaf(v, cz, odd ? ps : -ps);
        pw[(lk * 4 + q) * OSTR + ocol] = res;  // C row = lk*4+q
      }
    }

    // Coalesced NT store from wave-private LDS (same-wave ordering, no bar).
    float* __restrict__ og = out + (R0 + (size_t)t * RPT + w * 16) * DD;
#pragma unroll
    for (int jj = 0; jj < 4; ++jj) {
      const int f = jj * 64 + l;
      const int row = f >> 4, c4 = (f & 15) * 4;
      const f32x4 v = *(const f32x4*)&pw[row * OSTR + c4];
      __builtin_nontemporal_store(v, (f32x4*)(og + row * DD + c4));
    }
  }
}

// ---------------------------------------------------------------------------
// Fallback (no workspace table): R6's proven scalar kernel, invf path.
// ---------------------------------------------------------------------------
__global__ __launch_bounds__(256, 8) void apply_rot_fb(
    const float* __restrict__ x, const float* __restrict__ M,
    const float* __restrict__ invf, float* __restrict__ out) {
  __shared__ float lds[64 * LSTR];
  const int tid = threadIdx.x;
  const size_t R0 = (size_t)blockIdx.x * 64;
  const float4* __restrict__ xg = (const float4*)x + R0 * 16;
#pragma unroll
  for (int i = 0; i < 4; ++i) {
    const int f = i * 256 + tid;
    *(float4*)&lds[(f >> 4) * LSTR + (f & 15) * 4] = xg[f];
  }
  __syncthreads();
  const int r = tid & 63;
  const int h = __builtin_amdgcn_readfirstlane(tid >> 6);
  const float* __restrict__ Mh = M + h * 16;
  const float* __restrict__ xr = &lds[r * LSTR];
  float acc[16];
#pragma unroll
  for (int c = 0; c < 16; ++c) acc[c] = 0.0f;
#pragma unroll 4
  for (int k4 = 0; k4 < 16; ++k4) {
    const float4 xv = *(const float4*)&xr[k4 * 4];
    const float* __restrict__ m0 = Mh + k4 * 4 * DD;
#pragma unroll
    for (int c = 0; c < 16; ++c) acc[c] = fmaf(xv.x, m0[c], acc[c]);
#pragma unroll
    for (int c = 0; c < 16; ++c) acc[c] = fmaf(xv.y, m0[DD + c], acc[c]);
#pragma unroll
    for (int c = 0; c < 16; ++c) acc[c] = fmaf(xv.z, m0[2 * DD + c], acc[c]);
#pragma unroll
    for (int c = 0; c < 16; ++c) acc[c] = fmaf(xv.w, m0[3 * DD + c], acc[c]);
  }
  const int g = (int)R0 + r;
  const int spos = (g >> 4) & (SS - 1);
  float cz[8], sz[8];
#pragma unroll
  for (int d = 0; d < 8; ++d) {
    const float ang = (float)spos * invf[h * 8 + d];
    cz[d] = 32.0f * cosf(ang);
    sz[d] = 32.0f * sinf(ang);
  }
  float4 lov[2], hiv[2];
#pragma unroll
  for (int q = 0; q < 2; ++q) {
#pragma unroll
    for (int d = 0; d < 4; ++d) {
      const int dd = 4 * q + d;
      const float e = acc[2 * dd], o = acc[2 * dd + 1];
      ((float*)&lov[q])[d] = e * cz[dd] - o * sz[dd];
      ((float*)&hiv[q])[d] = e * sz[dd] + o * cz[dd];
    }
  }
  __syncthreads();
  float* __restrict__ orow = &lds[r * LSTR];
  *(float4*)&orow[8 * h + 0] = lov[0];
  *(float4*)&orow[8 * h + 4] = lov[1];
  *(float4*)&orow[32 + 8 * h + 0] = hiv[0];
  *(float4*)&orow[32 + 8 * h + 4] = hiv[1];
  __syncthreads();
  float4* __restrict__ og = (float4*)out + R0 * 16;
#pragma unroll
  for (int i = 0; i < 4; ++i) {
    const int f = i * 256 + tid;
    og[f] = *(float4*)&lds[(f >> 4) * LSTR + (f & 15) * 4];
  }
}

// ---------------------------------------------------------------------------
extern "C" void kernel_launch(void* const* d_in, const int* in_sizes, int n_in,
                              void* d_out, int out_size, void* d_ws,
                              size_t ws_size, hipStream_t stream) {
  const float* x = (const float*)d_in[0];       // (4, 8192, 1024) f32
  const float* matrix = (const float*)d_in[1];  // (64, 64) f32
  const float* thetas = (const float*)d_in[2];  // (32,) f32
  const float* tscale = (const float*)d_in[3];  // (1,) f32
  const float* invf = (const float*)d_in[4];    // (32,) f32
  const int* pairs = (const int*)d_in[5];       // (32, 2) i32
  float* out = (float*)d_out;

  // ws layout: M f32 (16KB) | Mhi u16 (8KB) | Mlo u16 (8KB) | tab f32 (2MB)
  float* M = (float*)d_ws;
  unsigned short* Mhi = (unsigned short*)(M + DD * DD);
  unsigned short* Mlo = Mhi + DD * DD;
  float* tab = (float*)(Mlo + DD * DD);
  const size_t need =
      (size_t)DD * DD * 4 + (size_t)DD * DD * 4 + (size_t)SS * 64 * 4;
  const bool have_tab = ws_size >= need;

  setup_GM<<<16, 256, 0, stream>>>(thetas, tscale, pairs, matrix, M, Mhi, Mlo);
  if (have_tab) {
    setup_table<<<(SS * 32) / 256, 256, 0, stream>>>(invf, tab);
    apply_rot<<<NBLK, TPB, 0, stream>>>(x, Mhi, Mlo, tab, out);
  } else {
    apply_rot_fb<<<NG / 64, 256, 0, stream>>>(x, M, invf, out);
  }
}